// Round 18
// baseline (719.891 us; speedup 1.0000x reference)
//
#include <hip/hip_runtime.h>
#include <hip/hip_cooperative_groups.h>
#include <hip/hip_bf16.h>
#include <math.h>

namespace cg = cooperative_groups;

// Problem constants (fixed by setup_inputs)
#define BB   4
#define DD   1024
#define TT   2048
#define NH   8
#define DKH  128
#define NROI 128

typedef __attribute__((ext_vector_type(8))) __bf16 bf16x8;
typedef __attribute__((ext_vector_type(4))) float  f32x4;

// Workspace layout (floats):
#define OFF_Q    0
#define OFF_KV   131072                  // val bf16 [B][T][D]
#define OFF_BS   (131072 + 4194304)      // BS f32 [B][256][D]
#define OFF_POOL (131072 + 8388608)      // pooled
#define POOL_FLOATS 655360
#define WS_F32_TOTAL (OFF_POOL + POOL_FLOATS)
// bf16 region at ws + WS_F32_TOTAL: Wkb [1M], Wvb [1M], Xt [8M].

__device__ __forceinline__ float bfu2f(unsigned short u) {
    return __uint_as_float(((unsigned int)u) << 16);
}

__device__ __forceinline__ void glds16(const __hip_bfloat16* g, __hip_bfloat16* l)
{
    __builtin_amdgcn_global_load_lds(
        (const __attribute__((address_space(1))) void*)g,
        (__attribute__((address_space(3))) void*)l, 16, 0, 0);
}

// ===========================================================================
// MEGA KERNEL (cooperative): all phases, grid 512 x 512 threads.
// Phase 1: zero out + weight convert + qproj + transpose (grid-stride)
// Phase 2: fused_kv (R17 structure exactly; one block per tile)
// Phase 3: bs_build   Phase 4: pool   Phase 5: out_gemm (K-split, atomics)
// Shared mem: 52224B union (= fused phase size; max of all phases).
// ===========================================================================
__global__ __launch_bounds__(512) void mega_kernel(
    const float* __restrict__ X, __hip_bfloat16* __restrict__ Xt,
    const float* __restrict__ Wk, const float* __restrict__ Wv,
    __hip_bfloat16* __restrict__ Wkb, __hip_bfloat16* __restrict__ Wvb,
    const float* __restrict__ cls, const float* __restrict__ Wq,
    const float* __restrict__ bq, float* __restrict__ q,
    const float* __restrict__ bk, const float* __restrict__ bv,
    __hip_bfloat16* __restrict__ val, float* __restrict__ BS,
    const int* __restrict__ rois, float* __restrict__ pooled,
    const float* __restrict__ w1, const float* __restrict__ b1,
    const float* __restrict__ w3, const float* __restrict__ b3,
    const float* __restrict__ w7, const float* __restrict__ b7,
    const float* __restrict__ w9, const float* __restrict__ b9,
    float* __restrict__ out)
{
    __shared__ __align__(16) char smem[52224];
    cg::grid_group grid = cg::this_grid();

    const int bid = blockIdx.x;      // 0..511
    const int tid = threadIdx.x;     // 0..511

    // ------------------------------------------------------------ Phase 1
    {
        // 1a: zero out (131072 floats)
        const int i0 = bid * 512 + tid;
        if (i0 < 131072) out[i0] = 0.f;

        // 1b: weight convert (262144 float4-quads over 262144 threads)
        {
            const int i = bid * 512 + tid;
            float4 a = reinterpret_cast<const float4*>(Wk)[i];
            float4 b = reinterpret_cast<const float4*>(Wv)[i];
            union P4 { __hip_bfloat16 h[4]; ushort4 u; } pa, pb;
            pa.h[0] = __float2bfloat16(a.x); pa.h[1] = __float2bfloat16(a.y);
            pa.h[2] = __float2bfloat16(a.z); pa.h[3] = __float2bfloat16(a.w);
            pb.h[0] = __float2bfloat16(b.x); pb.h[1] = __float2bfloat16(b.y);
            pb.h[2] = __float2bfloat16(b.z); pb.h[3] = __float2bfloat16(b.w);
            reinterpret_cast<ushort4*>(Wkb)[i] = pa.u;
            reinterpret_cast<ushort4*>(Wvb)[i] = pb.u;
        }

        // 1c: qproj — one 64-lane warp per output d (4096 warps total)
        {
            const int wid  = bid * 8 + (tid >> 6);
            const int lane = tid & 63;
            const int b = wid >> 10, d = wid & 1023;
            const float* crow = cls + (size_t)b * DD;
            const float* wrow = Wq + (size_t)d * DD;
            float acc = 0.f;
            for (int i = lane; i < DD; i += 64) acc += crow[i] * wrow[i];
            #pragma unroll
            for (int off = 32; off; off >>= 1) acc += __shfl_down(acc, off);
            if (lane == 0) q[(size_t)b * DD + d] = acc + bq[d];
        }

        // 1d: transpose+convert, 1024 tiles [64 d][128 t], 2 per block
        float* tile = (float*)smem;               // [64][129]
        for (int tl = bid; tl < 1024; tl += 512) {
            __syncthreads();                      // protect prior tile reads
            const int t0 = (tl & 15) * 128;
            const int d0 = ((tl >> 4) & 15) * 64;
            const int b  = tl >> 8;
            const float* src = X + ((size_t)(b * DD + d0)) * TT + t0;
            const int f4c = tid & 31;             // 0..31
            const int r0  = tid >> 5;             // 0..15
            #pragma unroll
            for (int i = 0; i < 4; ++i) {
                const int r = r0 + 16 * i;
                const float4 v = *reinterpret_cast<const float4*>(
                    &src[(size_t)r * TT + f4c * 4]);
                tile[r * 129 + f4c * 4 + 0] = v.x;
                tile[r * 129 + f4c * 4 + 1] = v.y;
                tile[r * 129 + f4c * 4 + 2] = v.z;
                tile[r * 129 + f4c * 4 + 3] = v.w;
            }
            __syncthreads();
            __hip_bfloat16* dst = Xt + ((size_t)(b * TT + t0)) * DD + d0;
            #pragma unroll
            for (int j = 0; j < 4; ++j) {
                const int task2 = tid + 512 * j;
                const int tq  = task2 >> 4;       // 0..127
                const int dq4 = task2 & 15;       // quad of d
                union { __hip_bfloat16 h[4]; ushort4 u; } P;
                P.h[0] = __float2bfloat16(tile[(dq4 * 4 + 0) * 129 + tq]);
                P.h[1] = __float2bfloat16(tile[(dq4 * 4 + 1) * 129 + tq]);
                P.h[2] = __float2bfloat16(tile[(dq4 * 4 + 2) * 129 + tq]);
                P.h[3] = __float2bfloat16(tile[(dq4 * 4 + 3) * 129 + tq]);
                *reinterpret_cast<ushort4*>(&dst[(size_t)tq * DD + dq4 * 4]) = P.u;
            }
        }
    }
    __threadfence();
    grid.sync();

    // ------------------------------------------------------------ Phase 2
    // fused_kv: R9/R12/R13/R17 structure EXACTLY (2-buffer, vmcnt(3), no setprio)
    {
        __hip_bfloat16* AsK = (__hip_bfloat16*)smem;          // [2][4096]
        __hip_bfloat16* AsV = AsK + 8192;
        __hip_bfloat16* Bsm = AsV + 8192;
        float* qs    = (float*)(smem + 49152);                // 128
        float* rdot  = qs + 128;                              // [2][128]
        float* rsq   = rdot + 256;                            // [2][128]
        float* p_lds = rsq + 256;                             // 128

        const int t0 = (bid & 15) * 128;
        const int m0 = ((bid >> 4) & 7) * 128;
        const int b  = bid >> 7;

        const int lane = tid & 63;
        const int w    = tid >> 6;
        const int wr   = w >> 2;
        const int wc   = w & 3;

        if (tid < 128) qs[tid] = q[(size_t)b * DD + m0 + tid];

        const int st_row = tid >> 2;
        const int st_g   = (tid & 3) ^ ((st_row >> 1) & 3);

        const __hip_bfloat16* WkS = Wkb + (size_t)(m0 + st_row) * DD + st_g * 8;
        const __hip_bfloat16* WvS = Wvb + (size_t)(m0 + st_row) * DD + st_g * 8;
        const __hip_bfloat16* XS  = Xt + ((size_t)(b * TT + t0 + st_row)) * DD + st_g * 8;
        const int ldsoff = (w * 16) * 32;

        f32x4 ak[4][2], av[4][2];
        #pragma unroll
        for (int i = 0; i < 4; ++i)
            #pragma unroll
            for (int j = 0; j < 2; ++j) {
                ak[i][j] = (f32x4){0.f, 0.f, 0.f, 0.f};
                av[i][j] = (f32x4){0.f, 0.f, 0.f, 0.f};
            }

        auto STAGE = [&](int buf, int k0) {
            glds16(WkS + k0, AsK + buf * 4096 + ldsoff);
            glds16(WvS + k0, AsV + buf * 4096 + ldsoff);
            glds16(XS  + k0, Bsm + buf * 4096 + ldsoff);
        };

        auto COMPUTE = [&](int buf) {
            const int g = lane >> 4;
            bf16x8 bfx[2], afk[4], afv[4];
            #pragma unroll
            for (int fn = 0; fn < 2; ++fn) {
                const int r = wc * 32 + fn * 16 + (lane & 15);
                const int s = g ^ ((r >> 1) & 3);
                bfx[fn] = *reinterpret_cast<const bf16x8*>(&Bsm[buf * 4096 + r * 32 + s * 8]);
            }
            #pragma unroll
            for (int fm = 0; fm < 4; ++fm) {
                const int r = wr * 64 + fm * 16 + (lane & 15);
                const int s = g ^ ((r >> 1) & 3);
                afk[fm] = *reinterpret_cast<const bf16x8*>(&AsK[buf * 4096 + r * 32 + s * 8]);
                afv[fm] = *reinterpret_cast<const bf16x8*>(&AsV[buf * 4096 + r * 32 + s * 8]);
            }
            #pragma unroll
            for (int fm = 0; fm < 4; ++fm)
                #pragma unroll
                for (int fn = 0; fn < 2; ++fn)
                    ak[fm][fn] = __builtin_amdgcn_mfma_f32_16x16x32_bf16(
                        afk[fm], bfx[fn], ak[fm][fn], 0, 0, 0);
            #pragma unroll
            for (int fm = 0; fm < 4; ++fm)
                #pragma unroll
                for (int fn = 0; fn < 2; ++fn)
                    av[fm][fn] = __builtin_amdgcn_mfma_f32_16x16x32_bf16(
                        afv[fm], bfx[fn], av[fm][fn], 0, 0, 0);
        };

        STAGE(0, 0);
        STAGE(1, 32);
        asm volatile("s_waitcnt lgkmcnt(0)" ::: "memory");
        int cur = 0;
        #pragma unroll 2
        for (int i = 0; i < 30; ++i) {
            asm volatile("s_waitcnt vmcnt(3)" ::: "memory");
            __builtin_amdgcn_s_barrier();
            COMPUTE(cur);
            __builtin_amdgcn_s_barrier();
            STAGE(cur, (i + 2) * 32);
            cur ^= 1;
        }
        asm volatile("s_waitcnt vmcnt(3)" ::: "memory");
        __builtin_amdgcn_s_barrier();
        COMPUTE(cur);
        cur ^= 1;
        asm volatile("s_waitcnt vmcnt(0)" ::: "memory");
        __builtin_amdgcn_s_barrier();
        COMPUTE(cur);

        // attention scalar per t
        const int lg = lane >> 4;
        #pragma unroll
        for (int fn = 0; fn < 2; ++fn) {
            float dp = 0.f, sp = 0.f;
            #pragma unroll
            for (int fm = 0; fm < 4; ++fm) {
                const int mb = wr * 64 + fm * 16 + lg * 4;
                #pragma unroll
                for (int r = 0; r < 4; ++r) {
                    const float kv = ak[fm][fn][r] + bk[m0 + mb + r];
                    dp += kv * qs[mb + r];
                    sp += kv * kv;
                }
            }
            dp += __shfl_xor(dp, 16); sp += __shfl_xor(sp, 16);
            dp += __shfl_xor(dp, 32); sp += __shfl_xor(sp, 32);
            if (lane < 16) {
                rdot[wr * 128 + wc * 32 + fn * 16 + lane] = dp;
                rsq[wr * 128 + wc * 32 + fn * 16 + lane]  = sp;
            }
        }
        __syncthreads();
        if (tid < 128) {
            const float dd = rdot[tid] + rdot[128 + tid];
            const float ss = rsq[tid] + rsq[128 + tid];
            float qn2 = 0.f;
            for (int j = 0; j < 128; ++j) qn2 += qs[j] * qs[j];
            const float c = dd / fmaxf(sqrtf(qn2) * sqrtf(ss), 1e-8f);
            p_lds[tid] = expf(fabsf(c));
        }
        __syncthreads();

        float pv[2];
        #pragma unroll
        for (int fn = 0; fn < 2; ++fn)
            pv[fn] = p_lds[wc * 32 + fn * 16 + (lane & 15)];

        const int tbase = t0 + wc * 32 + (lane & 15);
        #pragma unroll
        for (int fm = 0; fm < 4; ++fm) {
            const int m = m0 + wr * 64 + fm * 16 + lg * 4;
            const float4 b4 = *reinterpret_cast<const float4*>(&bv[m]);
            #pragma unroll
            for (int fn = 0; fn < 2; ++fn) {
                const int t = tbase + fn * 16;
                const f32x4 a = av[fm][fn];
                const float pf = pv[fn];
                union { __hip_bfloat16 h[4]; ushort4 u; } P;
                P.h[0] = __float2bfloat16((a[0] + b4.x) * pf);
                P.h[1] = __float2bfloat16((a[1] + b4.y) * pf);
                P.h[2] = __float2bfloat16((a[2] + b4.z) * pf);
                P.h[3] = __float2bfloat16((a[3] + b4.w) * pf);
                *reinterpret_cast<ushort4*>(&val[((size_t)(b * TT + t)) * DD + m]) = P.u;
            }
        }
    }
    __threadfence();
    grid.sync();

    // ------------------------------------------------------------ Phase 3
    // bs_build: 1024 tasks (b, g), 2 per block
    {
        const int task = bid * 2 + (tid >> 8);   // 0..1023
        const int b  = task >> 8;
        const int g  = task & 255;
        const int c4 = (tid & 255) * 4;
        const __hip_bfloat16* vb = val + ((size_t)b * TT + g * 8) * DD + c4;
        float a0 = 0.f, a1 = 0.f, a2 = 0.f, a3 = 0.f;
        #pragma unroll
        for (int j = 0; j < 8; ++j) {
            const ushort4 u = *reinterpret_cast<const ushort4*>(&vb[(size_t)j * DD]);
            a0 += bfu2f(u.x); a1 += bfu2f(u.y);
            a2 += bfu2f(u.z); a3 += bfu2f(u.w);
        }
        float4 r; r.x = a0; r.y = a1; r.z = a2; r.w = a3;
        *reinterpret_cast<float4*>(&BS[((size_t)b * 256 + g) * DD + c4]) = r;
    }
    __threadfence();
    grid.sync();

    // ------------------------------------------------------------ Phase 4
    // pool: 2560 tasks (n, z), 2 per block-iteration, 3 iterations
    {
        const int sub  = tid >> 8;               // 0/1
        const int stid = tid & 255;
        float* lacc = (float*)smem + sub * 1024; // [4][256]
        const int quarter = stid >> 6;
        const int lane    = stid & 63;
        const int c4      = lane * 4;

        for (int it = 0; it < 3; ++it) {
            const int task = bid * 2 + sub + it * 1024;
            const bool valid = task < 2560;      // uniform per block
            const int n = valid ? (task / 20) : 0;
            const int z = valid ? (task % 20) : 0;
            int sc, bin;
            if      (z == 0)  { sc = 0; bin = 0; }
            else if (z < 4)   { sc = 1; bin = z - 1; }
            else if (z < 11)  { sc = 2; bin = z - 4; }
            else              { sc = 3; bin = z - 11; }
            const int nbt[4]  = {1, 3, 7, 9};
            const int offt[4] = {0, 32768, 131072, 360448};
            const int nb  = nbt[sc];
            const int off = offt[sc];
            const int bidx = rois[n * 3 + 0];
            const int s    = rois[n * 3 + 1];
            const int e    = rois[n * 3 + 2];
            const int L    = e - s;
            const int bs  = s + (bin * L) / nb;
            const int be  = s + ((bin + 1) * L + nb - 1) / nb;
            const int cnt = be - bs;

            const __hip_bfloat16* vb = val + (size_t)bidx * TT * DD + sc * 256 + c4;
            const float* bsrc = BS + (size_t)bidx * 256 * DD + sc * 256 + c4;

            float a0 = 0.f, a1 = 0.f, a2 = 0.f, a3 = 0.f;
            const int g_lo = (bs + 7) >> 3;
            const int g_hi = be >> 3;

            if (valid) {
                if (g_lo >= g_hi) {
                    for (int t = bs + quarter; t < be; t += 4) {
                        const ushort4 u = *reinterpret_cast<const ushort4*>(&vb[(size_t)t * DD]);
                        a0 += bfu2f(u.x); a1 += bfu2f(u.y);
                        a2 += bfu2f(u.z); a3 += bfu2f(u.w);
                    }
                } else {
                    const int ngrp  = g_hi - g_lo;
                    const int nhead = g_lo * 8 - bs;
                    const int ntail = be - g_hi * 8;
                    const int nitems = ngrp + nhead + ntail;
                    for (int i = quarter; i < nitems; i += 4) {
                        if (i < ngrp) {
                            const float4 v = *reinterpret_cast<const float4*>(
                                &bsrc[(size_t)(g_lo + i) * DD]);
                            a0 += v.x; a1 += v.y; a2 += v.z; a3 += v.w;
                        } else if (i < ngrp + nhead) {
                            const int t = bs + (i - ngrp);
                            const ushort4 u = *reinterpret_cast<const ushort4*>(&vb[(size_t)t * DD]);
                            a0 += bfu2f(u.x); a1 += bfu2f(u.y);
                            a2 += bfu2f(u.z); a3 += bfu2f(u.w);
                        } else {
                            const int t = g_hi * 8 + (i - ngrp - nhead);
                            const ushort4 u = *reinterpret_cast<const ushort4*>(&vb[(size_t)t * DD]);
                            a0 += bfu2f(u.x); a1 += bfu2f(u.y);
                            a2 += bfu2f(u.z); a3 += bfu2f(u.w);
                        }
                    }
                }
            }
            __syncthreads();                      // lacc free for writes
            float4 r; r.x = a0; r.y = a1; r.z = a2; r.w = a3;
            *reinterpret_cast<float4*>(&lacc[quarter * 256 + c4]) = r;
            __syncthreads();
            if (valid) {
                const int ch = stid;
                const float v = (lacc[ch] + lacc[256 + ch] + lacc[512 + ch]
                                 + lacc[768 + ch]) / (float)cnt;
                pooled[off + ((size_t)n * 256 + ch) * nb + bin] = v;
            }
        }
    }
    __threadfence();
    grid.sync();

    // ------------------------------------------------------------ Phase 5
    // out_gemm: 1280 tasks (x,y,z), 2 per block-iteration, 2 iterations
    {
        const int sub  = tid >> 8;
        const int stid = tid & 255;
        float* Ps  = (float*)smem + sub * 2112;   // [32][33]
        float* Wsm = Ps + 1056;
        const int tx = stid & 15, ty = stid >> 4;

        for (int it = 0; it < 2; ++it) {
            const int task = bid * 2 + sub + it * 1024;
            const bool valid = task < 1280;       // uniform per block
            const int tdec = valid ? task : 0;
            const int x = tdec & 7, y = (tdec >> 3) & 3, z = tdec >> 5;
            int sc, kc;
            if      (z < 2)   { sc = 0; kc = z; }
            else if (z < 8)   { sc = 1; kc = z - 2; }
            else if (z < 22)  { sc = 2; kc = z - 8; }
            else              { sc = 3; kc = z - 22; }
            const int nbt[4]  = {1, 3, 7, 9};
            const int offt[4] = {0, 32768, 131072, 360448};
            const float* Wt[4] = {w1, w3, w7, w9};
            const float* Bt[4] = {b1, b3, b7, b9};
            const int nb  = nbt[sc];
            const int Kj  = 256 * nb;
            const float* P = pooled + offt[sc];
            const float* W = Wt[sc];
            const float* bias = Bt[sc];
            const int o0 = x * 32, n0 = y * 32, kbase = kc * 128;

            float acc[2][2] = {};
            for (int k0 = kbase; k0 < kbase + 128; k0 += 32) {
                __syncthreads();                  // previous tile consumed
                #pragma unroll
                for (int i = 0; i < 4; ++i) {
                    const int li = stid + i * 256;
                    const int r = li >> 5, k = li & 31;
                    Ps[r * 33 + k]  = P[(size_t)(n0 + r) * Kj + k0 + k];
                    Wsm[r * 33 + k] = W[(size_t)(o0 + r) * Kj + k0 + k];
                }
                __syncthreads();
                #pragma unroll
                for (int k = 0; k < 32; ++k) {
                    const float p0 = Ps[ty * 33 + k],  p1 = Ps[(ty + 16) * 33 + k];
                    const float w0 = Wsm[tx * 33 + k], w1v = Wsm[(tx + 16) * 33 + k];
                    acc[0][0] = fmaf(p0, w0,  acc[0][0]);
                    acc[0][1] = fmaf(p0, w1v, acc[0][1]);
                    acc[1][0] = fmaf(p1, w0,  acc[1][0]);
                    acc[1][1] = fmaf(p1, w1v, acc[1][1]);
                }
            }
            if (valid) {
                #pragma unroll
                for (int i = 0; i < 2; ++i) {
                    const int n = n0 + ty + 16 * i;
                    #pragma unroll
                    for (int jj = 0; jj < 2; ++jj) {
                        const int o = o0 + tx + 16 * jj;
                        const float add = (kc == 0) ? bias[o] : 0.f;
                        atomicAdd(&out[(size_t)n * DD + sc * 256 + o],
                                  acc[i][jj] + add);
                    }
                }
            }
            __syncthreads();                      // Ps/Wsm free for next it
        }
    }
}

// ===========================================================================
// Fallback path: the proven R17 kernels (used if cooperative launch fails).
// ===========================================================================
__global__ __launch_bounds__(256) void prep_kernel(
    const float* __restrict__ X, __hip_bfloat16* __restrict__ Xt,
    const float* __restrict__ Wk, const float* __restrict__ Wv,
    __hip_bfloat16* __restrict__ Wkb, __hip_bfloat16* __restrict__ Wvb,
    const float* __restrict__ cls, const float* __restrict__ Wq,
    const float* __restrict__ bq, float* __restrict__ q)
{
    __shared__ float tile[64][129];
    const int bx  = blockIdx.x;
    const int tid = threadIdx.x;

    if (bx < 1024) {
        const int t0 = (bx & 15) * 128;
        const int d0 = ((bx >> 4) & 15) * 64;
        const int b  = bx >> 8;
        const float* src = X + ((size_t)(b * DD + d0)) * TT + t0;
        const int f4c = tid & 31;
        const int r0  = tid >> 5;
        #pragma unroll
        for (int i = 0; i < 8; ++i) {
            const int r = r0 + 8 * i;
            const float4 v = *reinterpret_cast<const float4*>(&src[(size_t)r * TT + f4c * 4]);
            tile[r][f4c * 4 + 0] = v.x;
            tile[r][f4c * 4 + 1] = v.y;
            tile[r][f4c * 4 + 2] = v.z;
            tile[r][f4c * 4 + 3] = v.w;
        }
        __syncthreads();
        const int lane = tid & 63, w = tid >> 6;
        const int dq = (lane & 15) * 4;
        const int th = lane >> 4;
        __hip_bfloat16* dst = Xt + ((size_t)(b * TT + t0)) * DD + d0;
        #pragma unroll
        for (int i = 0; i < 8; ++i) {
            const int t = w * 4 + th + i * 16;
            union { __hip_bfloat16 h[4]; ushort4 u; } P;
            P.h[0] = __float2bfloat16(tile[dq + 0][t]);
            P.h[1] = __float2bfloat16(tile[dq + 1][t]);
            P.h[2] = __float2bfloat16(tile[dq + 2][t]);
            P.h[3] = __float2bfloat16(tile[dq + 3][t]);
            *reinterpret_cast<ushort4*>(&dst[(size_t)t * DD + dq]) = P.u;
        }
    } else if (bx < 2048) {
        const int i = (bx - 1024) * 256 + tid;
        float4 a = reinterpret_cast<const float4*>(Wk)[i];
        float4 b = reinterpret_cast<const float4*>(Wv)[i];
        union P4 { __hip_bfloat16 h[4]; ushort4 u; } pa, pb;
        pa.h[0] = __float2bfloat16(a.x); pa.h[1] = __float2bfloat16(a.y);
        pa.h[2] = __float2bfloat16(a.z); pa.h[3] = __float2bfloat16(a.w);
        pb.h[0] = __float2bfloat16(b.x); pb.h[1] = __float2bfloat16(b.y);
        pb.h[2] = __float2bfloat16(b.z); pb.h[3] = __float2bfloat16(b.w);
        reinterpret_cast<ushort4*>(Wkb)[i] = pa.u;
        reinterpret_cast<ushort4*>(Wvb)[i] = pb.u;
    } else {
        const int blk  = bx - 2048;
        const int b    = blk >> 8;
        const int dg   = blk & 255;
        const int warp = tid >> 6;
        const int lane = tid & 63;
        const int d    = dg * 4 + warp;
        const float* crow = cls + (size_t)b * DD;
        const float* wrow = Wq + (size_t)d * DD;
        float acc = 0.f;
        for (int i = lane; i < DD; i += 64) acc += crow[i] * wrow[i];
        #pragma unroll
        for (int off = 32; off; off >>= 1) acc += __shfl_down(acc, off);
        if (lane == 0) q[(size_t)b * DD + d] = acc + bq[d];
    }
}

__global__ __launch_bounds__(512) void fused_kv(
    const __hip_bfloat16* __restrict__ Wkb,
    const __hip_bfloat16* __restrict__ Wvb,
    const __hip_bfloat16* __restrict__ Xt,
    const float* __restrict__ bk, const float* __restrict__ bv,
    const float* __restrict__ q,
    __hip_bfloat16* __restrict__ val)
{
    const int t0 = blockIdx.x * 128;
    const int m0 = blockIdx.y * 128;
    const int b  = blockIdx.z;

    __shared__ __hip_bfloat16 AsK[2][128 * 32];
    __shared__ __hip_bfloat16 AsV[2][128 * 32];
    __shared__ __hip_bfloat16 Bs[2][128 * 32];
    __shared__ float qs[128];
    __shared__ float rdot[2][128];
    __shared__ float rsq[2][128];
    __shared__ float p_lds[128];

    const int tid  = threadIdx.x;
    const int lane = tid & 63;
    const int w    = tid >> 6;
    const int wr   = w >> 2;
    const int wc   = w & 3;

    if (tid < 128) qs[tid] = q[(size_t)b * DD + m0 + tid];

    const int st_row = tid >> 2;
    const int st_g   = (tid & 3) ^ ((st_row >> 1) & 3);

    const __hip_bfloat16* WkS = Wkb + (size_t)(m0 + st_row) * DD + st_g * 8;
    const __hip_bfloat16* WvS = Wvb + (size_t)(m0 + st_row) * DD + st_g * 8;
    const __hip_bfloat16* XS  = Xt + ((size_t)(b * TT + t0 + st_row)) * DD + st_g * 8;
    const int ldsoff = (w * 16) * 32;

    f32x4 ak[4][2], av[4][2];
    #pragma unroll
    for (int i = 0; i < 4; ++i)
        #pragma unroll
        for (int j = 0; j < 2; ++j) {
            ak[i][j] = (f32x4){0.f, 0.f, 0.f, 0.f};
            av[i][j] = (f32x4){0.f, 0.f, 0.f, 0.f};
        }

    auto STAGE = [&](int buf, int k0) {
        glds16(WkS + k0, AsK[buf] + ldsoff);
        glds16(WvS + k0, AsV[buf] + ldsoff);
        glds16(XS  + k0, Bs[buf]  + ldsoff);
    };

    auto COMPUTE = [&](int buf) {
        const int g = lane >> 4;
        bf16x8 bfx[2], afk[4], afv[4];
        #pragma unroll
        for (int fn = 0; fn < 2; ++fn) {
            const int r = wc * 32 + fn * 16 + (lane & 15);
            const int s = g ^ ((r >> 1) & 3);
            bfx[fn] = *reinterpret_cast<const bf16x8*>(&Bs[buf][r * 32 + s * 8]);
        }
        #pragma unroll
        for (int fm = 0; fm < 4; ++fm) {
            const int r = wr * 64 + fm * 16 + (lane & 15);
            const int s = g ^ ((r >> 1) & 3);
            afk[fm] = *reinterpret_cast<const bf16x8*>(&AsK[buf][r * 32 + s * 8]);
            afv[fm] = *reinterpret_cast<const bf16x8*>(&AsV[buf][r * 32 + s * 8]);
        }
        #pragma unroll
        for (int fm = 0; fm < 4; ++fm)
            #pragma unroll
            for (int fn = 0; fn < 2; ++fn)
                ak[fm][fn] = __builtin_amdgcn_mfma_f32_16x16x32_bf16(
                    afk[fm], bfx[fn], ak[fm][fn], 0, 0, 0);
        #pragma unroll
        for (int fm = 0; fm < 4; ++fm)
            #pragma unroll
            for (int fn = 0; fn < 2; ++fn)
                av[fm][fn] = __builtin_amdgcn_mfma_f32_16x16x32_bf16(
                    afv[fm], bfx[fn], av[fm][fn], 0, 0, 0);
    };

    STAGE(0, 0);
    STAGE(1, 32);
    asm volatile("s_waitcnt lgkmcnt(0)" ::: "memory");
    int cur = 0;
    #pragma unroll 2
    for (int i = 0; i < 30; ++i) {
        asm volatile("s_waitcnt vmcnt(3)" ::: "memory");
        __builtin_amdgcn_s_barrier();
        COMPUTE(cur);
        __builtin_amdgcn_s_barrier();
        STAGE(cur, (i + 2) * 32);
        cur ^= 1;
    }
    asm volatile("s_waitcnt vmcnt(3)" ::: "memory");
    __builtin_amdgcn_s_barrier();
    COMPUTE(cur);
    cur ^= 1;
    asm volatile("s_waitcnt vmcnt(0)" ::: "memory");
    __builtin_amdgcn_s_barrier();
    COMPUTE(cur);

    const int lg = lane >> 4;
    #pragma unroll
    for (int fn = 0; fn < 2; ++fn) {
        float dp = 0.f, sp = 0.f;
        #pragma unroll
        for (int fm = 0; fm < 4; ++fm) {
            const int mb = wr * 64 + fm * 16 + lg * 4;
            #pragma unroll
            for (int r = 0; r < 4; ++r) {
                const float kv = ak[fm][fn][r] + bk[m0 + mb + r];
                dp += kv * qs[mb + r];
                sp += kv * kv;
            }
        }
        dp += __shfl_xor(dp, 16); sp += __shfl_xor(sp, 16);
        dp += __shfl_xor(dp, 32); sp += __shfl_xor(sp, 32);
        if (lane < 16) {
            rdot[wr][wc * 32 + fn * 16 + lane] = dp;
            rsq[wr][wc * 32 + fn * 16 + lane]  = sp;
        }
    }
    __syncthreads();
    if (tid < 128) {
        const float dd = rdot[0][tid] + rdot[1][tid];
        const float ss = rsq[0][tid] + rsq[1][tid];
        float qn2 = 0.f;
        for (int j = 0; j < 128; ++j) qn2 += qs[j] * qs[j];
        const float c = dd / fmaxf(sqrtf(qn2) * sqrtf(ss), 1e-8f);
        p_lds[tid] = expf(fabsf(c));
    }
    __syncthreads();

    float pv[2];
    #pragma unroll
    for (int fn = 0; fn < 2; ++fn)
        pv[fn] = p_lds[wc * 32 + fn * 16 + (lane & 15)];

    const int tbase = t0 + wc * 32 + (lane & 15);
    #pragma unroll
    for (int fm = 0; fm < 4; ++fm) {
        const int m = m0 + wr * 64 + fm * 16 + lg * 4;
        const float4 b4 = *reinterpret_cast<const float4*>(&bv[m]);
        #pragma unroll
        for (int fn = 0; fn < 2; ++fn) {
            const int t = tbase + fn * 16;
            const f32x4 a = av[fm][fn];
            const float pf = pv[fn];
            union { __hip_bfloat16 h[4]; ushort4 u; } P;
            P.h[0] = __float2bfloat16((a[0] + b4.x) * pf);
            P.h[1] = __float2bfloat16((a[1] + b4.y) * pf);
            P.h[2] = __float2bfloat16((a[2] + b4.z) * pf);
            P.h[3] = __float2bfloat16((a[3] + b4.w) * pf);
            *reinterpret_cast<ushort4*>(&val[((size_t)(b * TT + t)) * DD + m]) = P.u;
        }
    }
}

__global__ __launch_bounds__(1024) void bs_build(
    const __hip_bfloat16* __restrict__ val, float* __restrict__ BS)
{
    const int b  = blockIdx.y;
    const int g  = blockIdx.x * 4 + (threadIdx.x >> 8);
    const int c4 = (threadIdx.x & 255) * 4;
    const __hip_bfloat16* vb = val + ((size_t)b * TT + g * 8) * DD + c4;
    float a0 = 0.f, a1 = 0.f, a2 = 0.f, a3 = 0.f;
    #pragma unroll
    for (int j = 0; j < 8; ++j) {
        const ushort4 u = *reinterpret_cast<const ushort4*>(&vb[(size_t)j * DD]);
        a0 += bfu2f(u.x); a1 += bfu2f(u.y);
        a2 += bfu2f(u.z); a3 += bfu2f(u.w);
    }
    float4 r; r.x = a0; r.y = a1; r.z = a2; r.w = a3;
    *reinterpret_cast<float4*>(&BS[((size_t)b * 256 + g) * DD + c4]) = r;
}

__global__ __launch_bounds__(256) void pool_kernel(
    const __hip_bfloat16* __restrict__ val, const float* __restrict__ BS,
    const int* __restrict__ rois, float* __restrict__ pooled)
{
    const int n = blockIdx.x;
    const int z = blockIdx.y;
    int sc, bin;
    if      (z == 0)  { sc = 0; bin = 0; }
    else if (z < 4)   { sc = 1; bin = z - 1; }
    else if (z < 11)  { sc = 2; bin = z - 4; }
    else              { sc = 3; bin = z - 11; }

    const int nbt[4]  = {1, 3, 7, 9};
    const int offt[4] = {0, 32768, 131072, 360448};
    const int nb  = nbt[sc];
    const int off = offt[sc];

    const int bidx = rois[n * 3 + 0];
    const int s    = rois[n * 3 + 1];
    const int e    = rois[n * 3 + 2];
    const int L    = e - s;

    const int bs  = s + (bin * L) / nb;
    const int be  = s + ((bin + 1) * L + nb - 1) / nb;
    const int cnt = be - bs;

    const int tid     = threadIdx.x;
    const int quarter = tid >> 6;
    const int lane    = tid & 63;
    const int c4      = lane * 4;

    const __hip_bfloat16* vb = val + (size_t)bidx * TT * DD + sc * 256 + c4;
    const float* bsrc = BS + (size_t)bidx * 256 * DD + sc * 256 + c4;

    float a0 = 0.f, a1 = 0.f, a2 = 0.f, a3 = 0.f;
    const int g_lo = (bs + 7) >> 3;
    const int g_hi = be >> 3;

    if (g_lo >= g_hi) {
        for (int t = bs + quarter; t < be; t += 4) {
            const ushort4 u = *reinterpret_cast<const ushort4*>(&vb[(size_t)t * DD]);
            a0 += bfu2f(u.x); a1 += bfu2f(u.y);
            a2 += bfu2f(u.z); a3 += bfu2f(u.w);
        }
    } else {
        const int ngrp  = g_hi - g_lo;
        const int nhead = g_lo * 8 - bs;
        const int ntail = be - g_hi * 8;
        const int nitems = ngrp + nhead + ntail;
        for (int i = quarter; i < nitems; i += 4) {
            if (i < ngrp) {
                const float4 v = *reinterpret_cast<const float4*>(
                    &bsrc[(size_t)(g_lo + i) * DD]);
                a0 += v.x; a1 += v.y; a2 += v.z; a3 += v.w;
            } else if (i < ngrp + nhead) {
                const int t = bs + (i - ngrp);
                const ushort4 u = *reinterpret_cast<const ushort4*>(&vb[(size_t)t * DD]);
                a0 += bfu2f(u.x); a1 += bfu2f(u.y);
                a2 += bfu2f(u.z); a3 += bfu2f(u.w);
            } else {
                const int t = g_hi * 8 + (i - ngrp - nhead);
                const ushort4 u = *reinterpret_cast<const ushort4*>(&vb[(size_t)t * DD]);
                a0 += bfu2f(u.x); a1 += bfu2f(u.y);
                a2 += bfu2f(u.z); a3 += bfu2f(u.w);
            }
        }
    }

    __shared__ float lacc[4][256];
    float4 r; r.x = a0; r.y = a1; r.z = a2; r.w = a3;
    *reinterpret_cast<float4*>(&lacc[quarter][c4]) = r;
    __syncthreads();

    const int ch = tid;
    const float v = (lacc[0][ch] + lacc[1][ch] + lacc[2][ch] + lacc[3][ch])
                    / (float)cnt;
    pooled[off + ((size_t)n * 256 + ch) * nb + bin] = v;
}

__global__ __launch_bounds__(256) void out_gemm(
    const float* __restrict__ pooled,
    const float* __restrict__ w1, const float* __restrict__ b1,
    const float* __restrict__ w3, const float* __restrict__ b3,
    const float* __restrict__ w7, const float* __restrict__ b7,
    const float* __restrict__ w9, const float* __restrict__ b9,
    float* __restrict__ out)
{
    const int z = blockIdx.z;
    int sc, kc;
    if      (z < 2)   { sc = 0; kc = z; }
    else if (z < 8)   { sc = 1; kc = z - 2; }
    else if (z < 22)  { sc = 2; kc = z - 8; }
    else              { sc = 3; kc = z - 22; }

    int nb, off; const float* W; const float* bias;
    switch (sc) {
        case 0:  nb = 1; off = 0;      W = w1; bias = b1; break;
        case 1:  nb = 3; off = 32768;  W = w3; bias = b3; break;
        case 2:  nb = 7; off = 131072; W = w7; bias = b7; break;
        default: nb = 9; off = 360448; W = w9; bias = b9; break;
    }
    const int Kj = 256 * nb;
    const float* P = pooled + off;

    const int o0 = blockIdx.x * 32;
    const int n0 = blockIdx.y * 32;
    const int kbase = kc * 128;

    __shared__ float Ps[32][33];
    __shared__ float Ws[32][33];

    const int tid = threadIdx.x;
    const int tx = tid & 15, ty = tid >> 4;
    float acc[2][2] = {};

    for (int k0 = kbase; k0 < kbase + 128; k0 += 32) {
        #pragma unroll
        for (int i = 0; i < 4; ++i) {
            const int li = tid + i * 256;
            const int r = li >> 5, k = li & 31;
            Ps[r][k] = P[(size_t)(n0 + r) * Kj + k0 + k];
            Ws[r][k] = W[(size_t)(o0 + r) * Kj + k0 + k];
        }
        __syncthreads();
        #pragma unroll
        for (int k = 0; k < 32; ++k) {
            const float p0 = Ps[ty][k],  p1 = Ps[ty + 16][k];
            const float w0 = Ws[tx][k],  w1v = Ws[tx + 16][k];
            acc[0][0] = fmaf(p0, w0,  acc[0][0]);
            acc[0][1] = fmaf(p0, w1v, acc[0][1]);
            acc[1][0] = fmaf(p1, w0,  acc[1][0]);
            acc[1][1] = fmaf(p1, w1v, acc[1][1]);
        }
        __syncthreads();
    }
    #pragma unroll
    for (int i = 0; i < 2; ++i) {
        const int n = n0 + ty + 16 * i;
        #pragma unroll
        for (int jj = 0; jj < 2; ++jj) {
            const int o = o0 + tx + 16 * jj;
            const float add = (kc == 0) ? bias[o] : 0.f;
            atomicAdd(&out[(size_t)n * DD + sc * 256 + o], acc[i][jj] + add);
        }
    }
}

// ---------------------------------------------------------------------------
extern "C" void kernel_launch(void* const* d_in, const int* in_sizes, int n_in,
                              void* d_out, int out_size, void* d_ws, size_t ws_size,
                              hipStream_t stream)
{
    const float* inp  = (const float*)d_in[0];
    const float* cls  = (const float*)d_in[1];
    const int*   rois = (const int*)  d_in[2];
    const float* Wq   = (const float*)d_in[3];
    const float* bq   = (const float*)d_in[4];
    const float* Wk   = (const float*)d_in[5];
    const float* bk   = (const float*)d_in[6];
    const float* Wv   = (const float*)d_in[7];
    const float* bv   = (const float*)d_in[8];
    const float* cw1  = (const float*)d_in[9];  const float* cb1 = (const float*)d_in[10];
    const float* cw3  = (const float*)d_in[11]; const float* cb3 = (const float*)d_in[12];
    const float* cw7  = (const float*)d_in[13]; const float* cb7 = (const float*)d_in[14];
    const float* cw9  = (const float*)d_in[15]; const float* cb9 = (const float*)d_in[16];

    float* out = (float*)d_out;
    float* ws  = (float*)d_ws;
    float* q      = ws + OFF_Q;
    __hip_bfloat16* val = (__hip_bfloat16*)(ws + OFF_KV);
    float* BS     = ws + OFF_BS;
    float* pooled = ws + OFF_POOL;
    __hip_bfloat16* bfb = (__hip_bfloat16*)(ws + WS_F32_TOTAL);
    __hip_bfloat16* Wkb = bfb;
    __hip_bfloat16* Wvb = bfb + 1048576;
    __hip_bfloat16* Xt  = bfb + 2097152;

    // Try the cooperative mega-kernel (1 dispatch). Deterministic fallback to
    // the proven 6-dispatch R17 path if cooperative launch is unsupported.
    void* kargs[] = {
        (void*)&inp, (void*)&Xt, (void*)&Wk, (void*)&Wv, (void*)&Wkb, (void*)&Wvb,
        (void*)&cls, (void*)&Wq, (void*)&bq, (void*)&q, (void*)&bk, (void*)&bv,
        (void*)&val, (void*)&BS, (void*)&rois, (void*)&pooled,
        (void*)&cw1, (void*)&cb1, (void*)&cw3, (void*)&cb3,
        (void*)&cw7, (void*)&cb7, (void*)&cw9, (void*)&cb9, (void*)&out
    };
    hipError_t err = hipLaunchCooperativeKernel(
        (const void*)mega_kernel, dim3(512), dim3(512), kargs, 0, stream);
    if (err == hipSuccess) return;
    (void)hipGetLastError();   // clear sticky error; run fallback path

    hipMemsetAsync(out, 0, (size_t)out_size * sizeof(float), stream);
    prep_kernel<<<dim3(3072), 256, 0, stream>>>(inp, Xt, Wk, Wv, Wkb, Wvb,
                                                cls, Wq, bq, q);
    fused_kv<<<dim3(TT / 128, DD / 128, BB), 512, 0, stream>>>(
        Wkb, Wvb, Xt, bk, bv, q, val);
    bs_build<<<dim3(64, BB), 1024, 0, stream>>>(val, BS);
    pool_kernel<<<dim3(NROI, 20), 256, 0, stream>>>(val, BS, rois, pooled);
    out_gemm<<<dim3(8, 4, 40), 256, 0, stream>>>(pooled, cw1, cb1, cw3, cb3,
                                                 cw7, cb7, cw9, cb9, out);
}

// Round 19
// 94.559 us; speedup vs baseline: 7.6131x; 7.6131x over previous
//
#include <hip/hip_runtime.h>
#include <hip/hip_bf16.h>
#include <math.h>

// Problem constants (fixed by setup_inputs)
#define BB   4
#define DD   1024
#define TT   2048
#define NH   8
#define DKH  128
#define NROI 128

typedef __attribute__((ext_vector_type(8))) __bf16 bf16x8;
typedef __attribute__((ext_vector_type(4))) float  f32x4;

// Workspace layout (floats):
#define OFF_Q    0
#define OFF_KV   131072                  // val bf16 [B][T][D]
#define OFF_BS   (131072 + 4194304)      // BS f32 [B][256][D]
#define OFF_POOL (131072 + 8388608)      // pooled
#define POOL_FLOATS 655360
#define WS_F32_TOTAL (OFF_POOL + POOL_FLOATS)
// bf16 region at ws + WS_F32_TOTAL: Wkb [1M], Wvb [1M], Xt [8M].

__device__ __forceinline__ float bfu2f(unsigned short u) {
    return __uint_as_float(((unsigned int)u) << 16);
}

// ---------------------------------------------------------------------------
// Merged prep: one dispatch, 3072 blocks.
//   blocks    0..1023 : X [B][D][T] f32 -> Xt [B][T][D] bf16 (64d x 128t tile)
//   blocks 1024..2047 : Wk/Wv f32 -> bf16 (float4-wide)
//   blocks 2048..3071 : q = cls @ Wq^T + bq
__global__ __launch_bounds__(256) void prep_kernel(
    const float* __restrict__ X, __hip_bfloat16* __restrict__ Xt,
    const float* __restrict__ Wk, const float* __restrict__ Wv,
    __hip_bfloat16* __restrict__ Wkb, __hip_bfloat16* __restrict__ Wvb,
    const float* __restrict__ cls, const float* __restrict__ Wq,
    const float* __restrict__ bq, float* __restrict__ q)
{
    __shared__ float tile[64][129];
    const int bx  = blockIdx.x;
    const int tid = threadIdx.x;

    if (bx < 1024) {
        const int t0 = (bx & 15) * 128;
        const int d0 = ((bx >> 4) & 15) * 64;
        const int b  = bx >> 8;
        const float* src = X + ((size_t)(b * DD + d0)) * TT + t0;
        const int f4c = tid & 31;            // float4 column 0..31
        const int r0  = tid >> 5;            // row 0..7
        #pragma unroll
        for (int i = 0; i < 8; ++i) {
            const int r = r0 + 8 * i;
            const float4 v = *reinterpret_cast<const float4*>(&src[(size_t)r * TT + f4c * 4]);
            tile[r][f4c * 4 + 0] = v.x;
            tile[r][f4c * 4 + 1] = v.y;
            tile[r][f4c * 4 + 2] = v.z;
            tile[r][f4c * 4 + 3] = v.w;
        }
        __syncthreads();
        const int lane = tid & 63, w = tid >> 6;
        const int dq = (lane & 15) * 4;
        const int th = lane >> 4;            // 0..3
        __hip_bfloat16* dst = Xt + ((size_t)(b * TT + t0)) * DD + d0;
        #pragma unroll
        for (int i = 0; i < 8; ++i) {
            const int t = w * 4 + th + i * 16;
            union { __hip_bfloat16 h[4]; ushort4 u; } P;
            P.h[0] = __float2bfloat16(tile[dq + 0][t]);
            P.h[1] = __float2bfloat16(tile[dq + 1][t]);
            P.h[2] = __float2bfloat16(tile[dq + 2][t]);
            P.h[3] = __float2bfloat16(tile[dq + 3][t]);
            *reinterpret_cast<ushort4*>(&dst[(size_t)t * DD + dq]) = P.u;
        }
    } else if (bx < 2048) {
        const int i = (bx - 1024) * 256 + tid;
        float4 a = reinterpret_cast<const float4*>(Wk)[i];
        float4 b = reinterpret_cast<const float4*>(Wv)[i];
        union P4 { __hip_bfloat16 h[4]; ushort4 u; } pa, pb;
        pa.h[0] = __float2bfloat16(a.x); pa.h[1] = __float2bfloat16(a.y);
        pa.h[2] = __float2bfloat16(a.z); pa.h[3] = __float2bfloat16(a.w);
        pb.h[0] = __float2bfloat16(b.x); pb.h[1] = __float2bfloat16(b.y);
        pb.h[2] = __float2bfloat16(b.z); pb.h[3] = __float2bfloat16(b.w);
        reinterpret_cast<ushort4*>(Wkb)[i] = pa.u;
        reinterpret_cast<ushort4*>(Wvb)[i] = pb.u;
    } else {
        const int blk  = bx - 2048;
        const int b    = blk >> 8;
        const int dg   = blk & 255;
        const int warp = tid >> 6;
        const int lane = tid & 63;
        const int d    = dg * 4 + warp;
        const float* crow = cls + (size_t)b * DD;
        const float* wrow = Wq + (size_t)d * DD;
        float acc = 0.f;
        for (int i = lane; i < DD; i += 64) acc += crow[i] * wrow[i];
        #pragma unroll
        for (int off = 32; off; off >>= 1) acc += __shfl_down(acc, off);
        if (lane == 0) q[(size_t)b * DD + d] = acc + bq[d];
    }
}

// ---------------------------------------------------------------------------
__device__ __forceinline__ void glds16(const __hip_bfloat16* g, __hip_bfloat16* l)
{
    __builtin_amdgcn_global_load_lds(
        (const __attribute__((address_space(1))) void*)g,
        (__attribute__((address_space(3))) void*)l, 16, 0, 0);
}

// Fused K-proj + cosine-attn + V-proj, 8-wave, counted-vmcnt pipeline (T4) —
// R9/R12/R13/R17 structure EXACTLY: 2-buffer, vmcnt(3), 52KB LDS = 3 blk/CU.
// HARD CONSTRAINTS (measured):
//  - VGPR <= 64 (R14 fused-BS, R11 setprio: VGPR 68 -> 2 blk/CU, dur +50%).
//  - LDS <= ~53KB for 3 blocks/CU (R10).
//  - NO s_setprio (R11).  NO grid.sync (R18: coop sync cost ~25x the gaps).
__global__ __launch_bounds__(512) void fused_kv(
    const __hip_bfloat16* __restrict__ Wkb,
    const __hip_bfloat16* __restrict__ Wvb,
    const __hip_bfloat16* __restrict__ Xt,
    const float* __restrict__ bk, const float* __restrict__ bv,
    const float* __restrict__ q,
    __hip_bfloat16* __restrict__ val)
{
    const int t0 = blockIdx.x * 128;
    const int m0 = blockIdx.y * 128;
    const int b  = blockIdx.z;

    __shared__ __hip_bfloat16 AsK[2][128 * 32];
    __shared__ __hip_bfloat16 AsV[2][128 * 32];
    __shared__ __hip_bfloat16 Bs[2][128 * 32];
    __shared__ float qs[128];
    __shared__ float rdot[2][128];
    __shared__ float rsq[2][128];
    __shared__ float p_lds[128];

    const int tid  = threadIdx.x;
    const int lane = tid & 63;
    const int w    = tid >> 6;
    const int wr   = w >> 2;
    const int wc   = w & 3;

    if (tid < 128) qs[tid] = q[(size_t)b * DD + m0 + tid];

    const int st_row = tid >> 2;
    const int st_g   = (tid & 3) ^ ((st_row >> 1) & 3);

    const __hip_bfloat16* WkS = Wkb + (size_t)(m0 + st_row) * DD + st_g * 8;
    const __hip_bfloat16* WvS = Wvb + (size_t)(m0 + st_row) * DD + st_g * 8;
    const __hip_bfloat16* XS  = Xt + ((size_t)(b * TT + t0 + st_row)) * DD + st_g * 8;
    const int ldsoff = (w * 16) * 32;

    f32x4 ak[4][2], av[4][2];
    #pragma unroll
    for (int i = 0; i < 4; ++i)
        #pragma unroll
        for (int j = 0; j < 2; ++j) {
            ak[i][j] = (f32x4){0.f, 0.f, 0.f, 0.f};
            av[i][j] = (f32x4){0.f, 0.f, 0.f, 0.f};
        }

    auto STAGE = [&](int buf, int k0) {
        glds16(WkS + k0, AsK[buf] + ldsoff);
        glds16(WvS + k0, AsV[buf] + ldsoff);
        glds16(XS  + k0, Bs[buf]  + ldsoff);
    };

    auto COMPUTE = [&](int buf) {
        const int g = lane >> 4;
        bf16x8 bfx[2], afk[4], afv[4];
        #pragma unroll
        for (int fn = 0; fn < 2; ++fn) {
            const int r = wc * 32 + fn * 16 + (lane & 15);
            const int s = g ^ ((r >> 1) & 3);
            bfx[fn] = *reinterpret_cast<const bf16x8*>(&Bs[buf][r * 32 + s * 8]);
        }
        #pragma unroll
        for (int fm = 0; fm < 4; ++fm) {
            const int r = wr * 64 + fm * 16 + (lane & 15);
            const int s = g ^ ((r >> 1) & 3);
            afk[fm] = *reinterpret_cast<const bf16x8*>(&AsK[buf][r * 32 + s * 8]);
            afv[fm] = *reinterpret_cast<const bf16x8*>(&AsV[buf][r * 32 + s * 8]);
        }
        #pragma unroll
        for (int fm = 0; fm < 4; ++fm)
            #pragma unroll
            for (int fn = 0; fn < 2; ++fn)
                ak[fm][fn] = __builtin_amdgcn_mfma_f32_16x16x32_bf16(
                    afk[fm], bfx[fn], ak[fm][fn], 0, 0, 0);
        #pragma unroll
        for (int fm = 0; fm < 4; ++fm)
            #pragma unroll
            for (int fn = 0; fn < 2; ++fn)
                av[fm][fn] = __builtin_amdgcn_mfma_f32_16x16x32_bf16(
                    afv[fm], bfx[fn], av[fm][fn], 0, 0, 0);
    };

    STAGE(0, 0);
    STAGE(1, 32);
    asm volatile("s_waitcnt lgkmcnt(0)" ::: "memory");
    int cur = 0;
    #pragma unroll 2
    for (int i = 0; i < 30; ++i) {
        asm volatile("s_waitcnt vmcnt(3)" ::: "memory");
        __builtin_amdgcn_s_barrier();
        COMPUTE(cur);
        __builtin_amdgcn_s_barrier();
        STAGE(cur, (i + 2) * 32);
        cur ^= 1;
    }
    asm volatile("s_waitcnt vmcnt(3)" ::: "memory");
    __builtin_amdgcn_s_barrier();
    COMPUTE(cur);
    cur ^= 1;
    asm volatile("s_waitcnt vmcnt(0)" ::: "memory");
    __builtin_amdgcn_s_barrier();
    COMPUTE(cur);

    const int lg = lane >> 4;
    #pragma unroll
    for (int fn = 0; fn < 2; ++fn) {
        float dp = 0.f, sp = 0.f;
        #pragma unroll
        for (int fm = 0; fm < 4; ++fm) {
            const int mb = wr * 64 + fm * 16 + lg * 4;
            #pragma unroll
            for (int r = 0; r < 4; ++r) {
                const float kv = ak[fm][fn][r] + bk[m0 + mb + r];
                dp += kv * qs[mb + r];
                sp += kv * kv;
            }
        }
        dp += __shfl_xor(dp, 16); sp += __shfl_xor(sp, 16);
        dp += __shfl_xor(dp, 32); sp += __shfl_xor(sp, 32);
        if (lane < 16) {
            rdot[wr][wc * 32 + fn * 16 + lane] = dp;
            rsq[wr][wc * 32 + fn * 16 + lane]  = sp;
        }
    }
    __syncthreads();
    if (tid < 128) {
        const float dd = rdot[0][tid] + rdot[1][tid];
        const float ss = rsq[0][tid] + rsq[1][tid];
        float qn2 = 0.f;
        for (int j = 0; j < 128; ++j) qn2 += qs[j] * qs[j];
        const float c = dd / fmaxf(sqrtf(qn2) * sqrtf(ss), 1e-8f);
        p_lds[tid] = expf(fabsf(c));
    }
    __syncthreads();

    float pv[2];
    #pragma unroll
    for (int fn = 0; fn < 2; ++fn)
        pv[fn] = p_lds[wc * 32 + fn * 16 + (lane & 15)];

    const int tbase = t0 + wc * 32 + (lane & 15);
    #pragma unroll
    for (int fm = 0; fm < 4; ++fm) {
        const int m = m0 + wr * 64 + fm * 16 + lg * 4;
        const float4 b4 = *reinterpret_cast<const float4*>(&bv[m]);
        #pragma unroll
        for (int fn = 0; fn < 2; ++fn) {
            const int t = tbase + fn * 16;
            const f32x4 a = av[fm][fn];
            const float pf = pv[fn];
            union { __hip_bfloat16 h[4]; ushort4 u; } P;
            P.h[0] = __float2bfloat16((a[0] + b4.x) * pf);
            P.h[1] = __float2bfloat16((a[1] + b4.y) * pf);
            P.h[2] = __float2bfloat16((a[2] + b4.z) * pf);
            P.h[3] = __float2bfloat16((a[3] + b4.w) * pf);
            *reinterpret_cast<ushort4*>(&val[((size_t)(b * TT + t)) * DD + m]) = P.u;
        }
    }
}

// ---------------------------------------------------------------------------
// Block-sum build: BS[b][g][c] = sum_{t in [g*8,(g+1)*8)} val[b][t][c], f32.
__global__ __launch_bounds__(1024) void bs_build(
    const __hip_bfloat16* __restrict__ val, float* __restrict__ BS)
{
    const int b  = blockIdx.y;
    const int g  = blockIdx.x * 4 + (threadIdx.x >> 8);
    const int c4 = (threadIdx.x & 255) * 4;
    const __hip_bfloat16* vb = val + ((size_t)b * TT + g * 8) * DD + c4;
    float a0 = 0.f, a1 = 0.f, a2 = 0.f, a3 = 0.f;
    #pragma unroll
    for (int j = 0; j < 8; ++j) {
        const ushort4 u = *reinterpret_cast<const ushort4*>(&vb[(size_t)j * DD]);
        a0 += bfu2f(u.x); a1 += bfu2f(u.y);
        a2 += bfu2f(u.z); a3 += bfu2f(u.w);
    }
    float4 r; r.x = a0; r.y = a1; r.z = a2; r.w = a3;
    *reinterpret_cast<float4*>(&BS[((size_t)b * 256 + g) * DD + c4]) = r;
}

// ---------------------------------------------------------------------------
// ROI pool via block-sums. Grid (NROI, 20): block = (roi, scale+bin).
__global__ __launch_bounds__(256) void pool_kernel(
    const __hip_bfloat16* __restrict__ val, const float* __restrict__ BS,
    const int* __restrict__ rois, float* __restrict__ pooled)
{
    const int n = blockIdx.x;
    const int z = blockIdx.y;
    int sc, bin;
    if      (z == 0)  { sc = 0; bin = 0; }
    else if (z < 4)   { sc = 1; bin = z - 1; }
    else if (z < 11)  { sc = 2; bin = z - 4; }
    else              { sc = 3; bin = z - 11; }

    const int nbt[4]  = {1, 3, 7, 9};
    const int offt[4] = {0, 32768, 131072, 360448};
    const int nb  = nbt[sc];
    const int off = offt[sc];

    const int bidx = rois[n * 3 + 0];
    const int s    = rois[n * 3 + 1];
    const int e    = rois[n * 3 + 2];
    const int L    = e - s;

    const int bs  = s + (bin * L) / nb;
    const int be  = s + ((bin + 1) * L + nb - 1) / nb;
    const int cnt = be - bs;

    const int tid     = threadIdx.x;
    const int quarter = tid >> 6;
    const int lane    = tid & 63;
    const int c4      = lane * 4;

    const __hip_bfloat16* vb = val + (size_t)bidx * TT * DD + sc * 256 + c4;
    const float* bsrc = BS + (size_t)bidx * 256 * DD + sc * 256 + c4;

    float a0 = 0.f, a1 = 0.f, a2 = 0.f, a3 = 0.f;
    const int g_lo = (bs + 7) >> 3;
    const int g_hi = be >> 3;

    if (g_lo >= g_hi) {
        for (int t = bs + quarter; t < be; t += 4) {
            const ushort4 u = *reinterpret_cast<const ushort4*>(&vb[(size_t)t * DD]);
            a0 += bfu2f(u.x); a1 += bfu2f(u.y);
            a2 += bfu2f(u.z); a3 += bfu2f(u.w);
        }
    } else {
        const int ngrp  = g_hi - g_lo;
        const int nhead = g_lo * 8 - bs;
        const int ntail = be - g_hi * 8;
        const int nitems = ngrp + nhead + ntail;
        for (int i = quarter; i < nitems; i += 4) {
            if (i < ngrp) {
                const float4 v = *reinterpret_cast<const float4*>(
                    &bsrc[(size_t)(g_lo + i) * DD]);
                a0 += v.x; a1 += v.y; a2 += v.z; a3 += v.w;
            } else if (i < ngrp + nhead) {
                const int t = bs + (i - ngrp);
                const ushort4 u = *reinterpret_cast<const ushort4*>(&vb[(size_t)t * DD]);
                a0 += bfu2f(u.x); a1 += bfu2f(u.y);
                a2 += bfu2f(u.z); a3 += bfu2f(u.w);
            } else {
                const int t = g_hi * 8 + (i - ngrp - nhead);
                const ushort4 u = *reinterpret_cast<const ushort4*>(&vb[(size_t)t * DD]);
                a0 += bfu2f(u.x); a1 += bfu2f(u.y);
                a2 += bfu2f(u.z); a3 += bfu2f(u.w);
            }
        }
    }

    __shared__ float lacc[4][256];
    float4 r; r.x = a0; r.y = a1; r.z = a2; r.w = a3;
    *reinterpret_cast<float4*>(&lacc[quarter][c4]) = r;
    __syncthreads();

    const int ch = tid;
    const float v = (lacc[0][ch] + lacc[1][ch] + lacc[2][ch] + lacc[3][ch])
                    / (float)cnt;
    pooled[off + ((size_t)n * 256 + ch) * nb + bin] = v;
}

// ---------------------------------------------------------------------------
// Final NT GEMM, fine K-split: 128-wide chunks -> 40 z-slices (1280 blocks).
__global__ __launch_bounds__(256) void out_gemm(
    const float* __restrict__ pooled,
    const float* __restrict__ w1, const float* __restrict__ b1,
    const float* __restrict__ w3, const float* __restrict__ b3,
    const float* __restrict__ w7, const float* __restrict__ b7,
    const float* __restrict__ w9, const float* __restrict__ b9,
    float* __restrict__ out)
{
    const int z = blockIdx.z;
    int sc, kc;
    if      (z < 2)   { sc = 0; kc = z; }
    else if (z < 8)   { sc = 1; kc = z - 2; }
    else if (z < 22)  { sc = 2; kc = z - 8; }
    else              { sc = 3; kc = z - 22; }

    int nb, off; const float* W; const float* bias;
    switch (sc) {
        case 0:  nb = 1; off = 0;      W = w1; bias = b1; break;
        case 1:  nb = 3; off = 32768;  W = w3; bias = b3; break;
        case 2:  nb = 7; off = 131072; W = w7; bias = b7; break;
        default: nb = 9; off = 360448; W = w9; bias = b9; break;
    }
    const int Kj = 256 * nb;
    const float* P = pooled + off;

    const int o0 = blockIdx.x * 32;
    const int n0 = blockIdx.y * 32;
    const int kbase = kc * 128;

    __shared__ float Ps[32][33];
    __shared__ float Ws[32][33];

    const int tid = threadIdx.x;
    const int tx = tid & 15, ty = tid >> 4;
    float acc[2][2] = {};

    for (int k0 = kbase; k0 < kbase + 128; k0 += 32) {
        #pragma unroll
        for (int i = 0; i < 4; ++i) {
            const int li = tid + i * 256;
            const int r = li >> 5, k = li & 31;
            Ps[r][k] = P[(size_t)(n0 + r) * Kj + k0 + k];
            Ws[r][k] = W[(size_t)(o0 + r) * Kj + k0 + k];
        }
        __syncthreads();
        #pragma unroll
        for (int k = 0; k < 32; ++k) {
            const float p0 = Ps[ty][k],  p1 = Ps[ty + 16][k];
            const float w0 = Ws[tx][k],  w1v = Ws[tx + 16][k];
            acc[0][0] = fmaf(p0, w0,  acc[0][0]);
            acc[0][1] = fmaf(p0, w1v, acc[0][1]);
            acc[1][0] = fmaf(p1, w0,  acc[1][0]);
            acc[1][1] = fmaf(p1, w1v, acc[1][1]);
        }
        __syncthreads();
    }
    #pragma unroll
    for (int i = 0; i < 2; ++i) {
        const int n = n0 + ty + 16 * i;
        #pragma unroll
        for (int jj = 0; jj < 2; ++jj) {
            const int o = o0 + tx + 16 * jj;
            const float add = (kc == 0) ? bias[o] : 0.f;
            atomicAdd(&out[(size_t)n * DD + sc * 256 + o], acc[i][jj] + add);
        }
    }
}

// ---------------------------------------------------------------------------
extern "C" void kernel_launch(void* const* d_in, const int* in_sizes, int n_in,
                              void* d_out, int out_size, void* d_ws, size_t ws_size,
                              hipStream_t stream)
{
    const float* inp  = (const float*)d_in[0];
    const float* cls  = (const float*)d_in[1];
    const int*   rois = (const int*)  d_in[2];
    const float* Wq   = (const float*)d_in[3];
    const float* bq   = (const float*)d_in[4];
    const float* Wk   = (const float*)d_in[5];
    const float* bk   = (const float*)d_in[6];
    const float* Wv   = (const float*)d_in[7];
    const float* bv   = (const float*)d_in[8];
    const float* cw1  = (const float*)d_in[9];  const float* cb1 = (const float*)d_in[10];
    const float* cw3  = (const float*)d_in[11]; const float* cb3 = (const float*)d_in[12];
    const float* cw7  = (const float*)d_in[13]; const float* cb7 = (const float*)d_in[14];
    const float* cw9  = (const float*)d_in[15]; const float* cb9 = (const float*)d_in[16];

    float* out = (float*)d_out;
    float* ws  = (float*)d_ws;
    float* q      = ws + OFF_Q;
    __hip_bfloat16* val = (__hip_bfloat16*)(ws + OFF_KV);
    float* BS     = ws + OFF_BS;
    float* pooled = ws + OFF_POOL;
    __hip_bfloat16* bfb = (__hip_bfloat16*)(ws + WS_F32_TOTAL);
    __hip_bfloat16* Wkb = bfb;
    __hip_bfloat16* Wvb = bfb + 1048576;
    __hip_bfloat16* Xt  = bfb + 2097152;

    hipMemsetAsync(out, 0, (size_t)out_size * sizeof(float), stream);
    prep_kernel<<<dim3(3072), 256, 0, stream>>>(inp, Xt, Wk, Wv, Wkb, Wvb,
                                                cls, Wq, bq, q);
    fused_kv<<<dim3(TT / 128, DD / 128, BB), 512, 0, stream>>>(
        Wkb, Wvb, Xt, bk, bv, q, val);
    bs_build<<<dim3(64, BB), 1024, 0, stream>>>(val, BS);
    pool_kernel<<<dim3(NROI, 20), 256, 0, stream>>>(val, BS, rois, pooled);
    out_gemm<<<dim3(8, 4, 40), 256, 0, stream>>>(pooled, cw1, cb1, cw3, cb3,
                                                 cw7, cb7, cw9, cb9, out);
}